// Round 1
// baseline (390.620 us; speedup 1.0000x reference)
//
#include <hip/hip_runtime.h>

// FeatureSampler: BEVFormer-style multi-cam multi-level bilinear feature sampling.
// B=2 batches, N=6 cameras, C=256 channels, M=900 queries, 4 levels.
// Inputs (fp32): feat0 (2,6,256,116,200), feat1 (2,6,256,58,100),
//                feat2 (2,6,256,29,50),  feat3 (2,6,256,15,25),
//                reference_points (2,900,3), lidar2img (2,6,4,4).
// Output (fp32): (2,900,256).
//
// Simplification: reference's per-level gx=(px/W)*2-1 followed by grid_sample's
// x=(gx+1)*(W/2)-0.5 collapses to x = px-0.5 for EVERY level -> one projection
// per (b,m,n), per-level work is only bounds-check + gather.

static constexpr float EPSV = 1e-5f;
static constexpr int Bn = 2, Nn = 6, Cn = 256, Mn = 900;

__global__ __launch_bounds__(256) void FeatureSampler_74062416052404_kernel(
    const float* __restrict__ f0, const float* __restrict__ f1,
    const float* __restrict__ f2, const float* __restrict__ f3,
    const float* __restrict__ refp, const float* __restrict__ l2i,
    float* __restrict__ out)
{
    const int bm = blockIdx.x;          // 0 .. B*M-1
    const int b  = bm / Mn;
    const int m  = bm - b * Mn;
    const int c  = threadIdx.x;         // channel 0..255

    // Denormalized reference point (block-uniform).
    const float rx = refp[(b * Mn + m) * 3 + 0] * 122.4f - 61.2f;
    const float ry = refp[(b * Mn + m) * 3 + 1] * 122.4f - 61.2f;
    const float rz = refp[(b * Mn + m) * 3 + 2] * 20.0f  - 10.0f;

    const float* const feats[4] = {f0, f1, f2, f3};
    constexpr int Hs[4] = {116, 58, 29, 15};
    constexpr int Ws[4] = {200, 100, 50, 25};

    float acc  = 0.0f;   // sum over n, levels of weighted bilinear samples
    float wsum = 0.0f;   // number of valid cameras

    for (int n = 0; n < Nn; ++n) {
        const float* L = l2i + (size_t)(b * Nn + n) * 16;
        const float cx = L[0] * rx + L[1] * ry + L[2]  * rz + L[3];
        const float cy = L[4] * rx + L[5] * ry + L[6]  * rz + L[7];
        const float cz = L[8] * rx + L[9] * ry + L[10] * rz + L[11];

        // valid = z > EPS; invalid cameras contribute 0 to numerator AND denominator.
        if (!(cz > EPSV)) continue;     // block-uniform branch, no divergence
        wsum += 1.0f;

        const float inv = 1.0f / (cz + EPSV);
        const float x   = cx * inv - 0.5f;   // same pixel coord for all levels
        const float y   = cy * inv - 0.5f;
        const float x0f = floorf(x);
        const float y0f = floorf(y);
        const float x1f = x0f + 1.0f;
        const float y1f = y0f + 1.0f;
        const float wx1 = x - x0f, wx0 = 1.0f - wx1;
        const float wy1 = y - y0f, wy0 = 1.0f - wy1;

#pragma unroll
        for (int l = 0; l < 4; ++l) {
            const int H = Hs[l], W = Ws[l];
            // Per-corner validity evaluated in float domain (x0f may be huge;
            // int conversion only happens once we know it's in [-1, W-1]).
            const bool vx0 = (x0f >= 0.0f) & (x0f < (float)W);
            const bool vx1 = (x1f >= 0.0f) & (x1f < (float)W);
            const bool vy0 = (y0f >= 0.0f) & (y0f < (float)H);
            const bool vy1 = (y1f >= 0.0f) & (y1f < (float)H);
            if (!((vx0 | vx1) & (vy0 | vy1))) continue;  // uniform skip

            // Safe now: x0f in [-1, W-1], y0f in [-1, H-1].
            const int xi0 = (int)x0f;
            const int yi0 = (int)y0f;
            const float* base =
                feats[l] + (size_t)((b * Nn + n) * Cn + c) * (H * W);

            float s = 0.0f;
            if (vx0 & vy0) s += wx0 * wy0 * base[yi0 * W + xi0];
            if (vx1 & vy0) s += wx1 * wy0 * base[yi0 * W + xi0 + 1];
            if (vx0 & vy1) s += wx0 * wy1 * base[(yi0 + 1) * W + xi0];
            if (vx1 & vy1) s += wx1 * wy1 * base[(yi0 + 1) * W + xi0 + 1];
            acc += s;
        }
    }

    // mean over 4 levels, masked mean over cameras
    out[(size_t)(b * Mn + m) * Cn + c] = acc * 0.25f / (wsum + EPSV);
}

extern "C" void kernel_launch(void* const* d_in, const int* in_sizes, int n_in,
                              void* d_out, int out_size, void* d_ws, size_t ws_size,
                              hipStream_t stream) {
    const float* f0   = (const float*)d_in[0];
    const float* f1   = (const float*)d_in[1];
    const float* f2   = (const float*)d_in[2];
    const float* f3   = (const float*)d_in[3];
    const float* refp = (const float*)d_in[4];
    const float* l2i  = (const float*)d_in[5];
    float* out = (float*)d_out;

    dim3 grid(Bn * Mn);   // 1800 blocks, one per (b, m)
    dim3 block(256);      // one thread per channel
    FeatureSampler_74062416052404_kernel<<<grid, block, 0, stream>>>(
        f0, f1, f2, f3, refp, l2i, out);
}